// Round 7
// baseline (21659.845 us; speedup 1.0000x reference)
//
#include <hip/hip_runtime.h>
#include <hip/hip_cooperative_groups.h>

namespace cg = cooperative_groups;

#define T_STEPS 512
#define BATCH   64
#define DIM     1024
#define HID     1024
#define G4      4096   // 4*HID

typedef __attribute__((ext_vector_type(8))) short s8v;    // 8 bf16 = 4 VGPR
typedef __attribute__((ext_vector_type(4))) float f32x4;

__device__ __forceinline__ unsigned short f2bf(float f) {
    unsigned int u = __float_as_uint(f);
    u = u + 0x7FFFu + ((u >> 16) & 1u);       // RNE; values bounded, no inf/nan
    return (unsigned short)(u >> 16);
}
__device__ __forceinline__ float bf2f(unsigned short s) {
    return __uint_as_float(((unsigned int)s) << 16);
}

// ---------------------------------------------------------------------------
// Fragment convention (A and B share it -> result exact for any HW k-order):
//   A: row = l&15, k = ks*32 + (l>>4)*8 + e     (row = batch within m-tile)
//   B: col = l&15, k = ks*32 + (l>>4)*8 + e     (col = gate-col c)
//   D (m89-verified): col = l&15, row = (l>>4)*4 + reg
// Packed planes (hi/lo separate):
//   xP[t][ks<32][m][l][e]   : idx = (((t*32+ks)*4+m)*64+l)*8+e
//   wP[bid][ks<64][l][e]    : ks<32 -> W_ih, ks>=32 -> W_hh
//   hP[par][ks<32][m][l][e]
// All layouts identical to the PASSING v4 kernel (absmax 0.0039).
// ---------------------------------------------------------------------------

__global__ __launch_bounds__(256) void pack_x(
    const float* __restrict__ inp, unsigned short* __restrict__ hi,
    unsigned short* __restrict__ lo)
{
    const size_t tau = (size_t)blockIdx.x * 256 + threadIdx.x;  // < 4,194,304
    const int l  = (int)(tau & 63);
    const int m  = (int)((tau >> 6) & 3);
    const int ks = (int)((tau >> 8) & 31);
    const int t  = (int)(tau >> 13);
    const int b  = 16 * m + (l & 15);
    const int k  = ks * 32 + (l >> 4) * 8;
    const float* src = inp + ((size_t)t * BATCH + b) * DIM + k;
    float f[8];
    *(float4*)&f[0] = *(const float4*)src;
    *(float4*)&f[4] = *(const float4*)(src + 4);
    s8v vh, vl;
#pragma unroll
    for (int e = 0; e < 8; ++e) {
        const unsigned short h8 = f2bf(f[e]);
        vh[e] = (short)h8;
        vl[e] = (short)f2bf(f[e] - bf2f(h8));
    }
    *(s8v*)(hi + tau * 8) = vh;
    *(s8v*)(lo + tau * 8) = vl;
}

__global__ __launch_bounds__(256) void pack_w(
    const float* __restrict__ Wih, const float* __restrict__ Whh,
    unsigned short* __restrict__ hi, unsigned short* __restrict__ lo)
{
    const size_t tau = (size_t)blockIdx.x * 256 + threadIdx.x;  // < 1,048,576
    const int l   = (int)(tau & 63);
    const int ks  = (int)((tau >> 6) & 63);
    const int bid = (int)(tau >> 12);
    const int c   = l & 15;
    const int n   = (c >> 2) * HID + bid * 4 + (c & 3);
    const int k   = ks * 32 + (l >> 4) * 8;
    const float* src = (k < DIM) ? (Wih + (size_t)n * DIM + k)
                                 : (Whh + (size_t)n * HID + (k - DIM));
    float f[8];
    *(float4*)&f[0] = *(const float4*)src;
    *(float4*)&f[4] = *(const float4*)(src + 4);
    s8v vh, vl;
#pragma unroll
    for (int e = 0; e < 8; ++e) {
        const unsigned short h8 = f2bf(f[e]);
        vh[e] = (short)h8;
        vl[e] = (short)f2bf(f[e] - bf2f(h8));
    }
    *(s8v*)(hi + tau * 8) = vh;
    *(s8v*)(lo + tau * 8) = vl;
}

__global__ __launch_bounds__(256) void pack_h0(
    const float* __restrict__ h0, unsigned short* __restrict__ hi,
    unsigned short* __restrict__ lo)
{
    const size_t tau = (size_t)blockIdx.x * 256 + threadIdx.x;  // < 8192 (par=0)
    const int l  = (int)(tau & 63);
    const int m  = (int)((tau >> 6) & 3);
    const int ks = (int)(tau >> 8);
    const int b  = 16 * m + (l & 15);
    const int j  = ks * 32 + (l >> 4) * 8;
    const float* src = h0 + (size_t)b * HID + j;
    float f[8];
    *(float4*)&f[0] = *(const float4*)src;
    *(float4*)&f[4] = *(const float4*)(src + 4);
    s8v vh, vl;
#pragma unroll
    for (int e = 0; e < 8; ++e) {
        const unsigned short h8 = f2bf(f[e]);
        vh[e] = (short)h8;
        vl[e] = (short)f2bf(f[e] - bf2f(h8));
    }
    *(s8v*)(hi + tau * 8) = vh;
    *(s8v*)(lo + tau * 8) = vl;
}

// ---------------------------------------------------------------------------
// Persistent cooperative LSTM: ONE dispatch, 256 blocks x 512 threads.
// Loop body = v4's proven per-step structure; grid.sync() replaces the
// kernel boundary (eliminates ~10us/step launch overhead that v4/v6
// measurements isolated as the dominant cost).
// wave wv = mg*4+kh: mg -> m-tiles 2mg,2mg+1; kh 0,1 -> x planes (ks kh*16..),
// kh 2,3 -> h planes (ks (kh-2)*16..). W rows: ks = kh*16 (0..31 W_ih,
// 32..63 W_hh). 3-pass split precision. c-state in LDS; biases in registers.
// ---------------------------------------------------------------------------
__global__ __launch_bounds__(512) void lstm_persist(
    const unsigned short* __restrict__ xPHi, const unsigned short* __restrict__ xPLo,
    const unsigned short* __restrict__ wPHi, const unsigned short* __restrict__ wPLo,
    unsigned short* hPHi, unsigned short* hPLo,      // read par, write par^1
    const float* __restrict__ c0,
    const float* __restrict__ bih, const float* __restrict__ bhh,
    float* __restrict__ out, float* __restrict__ tailp)
{
    cg::grid_group grid = cg::this_grid();

    __shared__ float part_s[8][64][8];    // 16 KB
    __shared__ float gates_s[64][17];     // 4.4 KB
    __shared__ float c_s[64][4];          // persistent cell state, 1 KB

    const int bid = blockIdx.x;
    const int tid = threadIdx.x;
    const int wv  = __builtin_amdgcn_readfirstlane(tid >> 6);
    const int l   = tid & 63;
    const int mg  = wv >> 2;             // 0..1
    const int kh  = wv & 3;              // 0..3
    const int m0  = 2 * mg, m1 = 2 * mg + 1;

    // init c state + hoist biases (tid<256 handles (b, jj))
    float bsum[4];
    if (tid < 256) {
        const int b  = tid >> 2;
        const int jj = tid & 3;
        const int j  = bid * 4 + jj;
        c_s[b][jj] = c0[b * HID + j];
#pragma unroll
        for (int g = 0; g < 4; ++g)
            bsum[g] = bih[g * HID + j] + bhh[g * HID + j];
    }
    __syncthreads();

    const unsigned short* bHiP = wPHi + ((size_t)bid * 64 + kh * 16) * 512;
    const unsigned short* bLoP = wPLo + ((size_t)bid * 64 + kh * 16) * 512;

#define LDA(P, i, m) (*(const s8v*)((P) + ((size_t)(i) * 2048 + (m) * 512 + l * 8)))
#define LDB(P, i)    (*(const s8v*)((P) + ((size_t)(i) * 512 + l * 8)))

    for (int t = 0; t < T_STEPS; ++t) {
        const int par = t & 1;

        const unsigned short *aHi, *aLo;
        if (kh < 2) {
            const size_t base = (((size_t)t * 32 + kh * 16) * 4) * 512;
            aHi = xPHi + base;  aLo = xPLo + base;
        } else {
            const size_t base = (((size_t)par * 32 + (kh - 2) * 16) * 4) * 512;
            aHi = hPHi + base;  aLo = hPLo + base;
        }

        f32x4 acc0 = {0.f, 0.f, 0.f, 0.f};
        f32x4 acc1 = {0.f, 0.f, 0.f, 0.f};

        s8v A0h = LDA(aHi, 0, m0), A0l = LDA(aLo, 0, m0);
        s8v A1h = LDA(aHi, 0, m1), A1l = LDA(aLo, 0, m1);
        s8v Bh  = LDB(bHiP, 0),    Bl  = LDB(bLoP, 0);

#pragma unroll 4
        for (int i = 0; i < 16; ++i) {
            s8v nA0h, nA0l, nA1h, nA1l, nBh, nBl;
            if (i < 15) {
                nA0h = LDA(aHi, i + 1, m0); nA0l = LDA(aLo, i + 1, m0);
                nA1h = LDA(aHi, i + 1, m1); nA1l = LDA(aLo, i + 1, m1);
                nBh  = LDB(bHiP, i + 1);    nBl  = LDB(bLoP, i + 1);
            }
            acc0 = __builtin_amdgcn_mfma_f32_16x16x32_bf16(A0h, Bh, acc0, 0, 0, 0);
            acc1 = __builtin_amdgcn_mfma_f32_16x16x32_bf16(A1h, Bh, acc1, 0, 0, 0);
            acc0 = __builtin_amdgcn_mfma_f32_16x16x32_bf16(A0h, Bl, acc0, 0, 0, 0);
            acc1 = __builtin_amdgcn_mfma_f32_16x16x32_bf16(A1h, Bl, acc1, 0, 0, 0);
            acc0 = __builtin_amdgcn_mfma_f32_16x16x32_bf16(A0l, Bh, acc0, 0, 0, 0);
            acc1 = __builtin_amdgcn_mfma_f32_16x16x32_bf16(A1l, Bh, acc1, 0, 0, 0);
            A0h = nA0h; A0l = nA0l; A1h = nA1h; A1l = nA1l; Bh = nBh; Bl = nBl;
        }

        // --- 4-way k-reduce through LDS (2 barriers) ---
        *(f32x4*)&part_s[wv][l][0] = acc0;
        *(f32x4*)&part_s[wv][l][4] = acc1;
        __syncthreads();
        if (tid < 128) {
            const int mg2 = tid >> 6, l2 = tid & 63;
            f32x4 s0 = {0.f, 0.f, 0.f, 0.f};
            f32x4 s1 = {0.f, 0.f, 0.f, 0.f};
#pragma unroll
            for (int k = 0; k < 4; ++k) {
                s0 += *(const f32x4*)&part_s[mg2 * 4 + k][l2][0];
                s1 += *(const f32x4*)&part_s[mg2 * 4 + k][l2][4];
            }
            const int c = l2 & 15, rb = (l2 >> 4) * 4;
#pragma unroll
            for (int r = 0; r < 4; ++r) {
                gates_s[16 * (2 * mg2 + 0) + rb + r][c] = s0[r];
                gates_s[16 * (2 * mg2 + 1) + rb + r][c] = s1[r];
            }
        }
        __syncthreads();

        // --- elementwise LSTM cell update + h repack for next step ---
        if (tid < 256) {
            const int b  = tid >> 2;
            const int jj = tid & 3;
            const int j  = bid * 4 + jj;
            const float pre_i = gates_s[b][0  + jj] + bsum[0];
            const float pre_f = gates_s[b][4  + jj] + bsum[1];
            const float pre_g = gates_s[b][8  + jj] + bsum[2];
            const float pre_o = gates_s[b][12 + jj] + bsum[3];
            const float ig = 1.0f / (1.0f + __expf(-pre_i));
            const float fg = 1.0f / (1.0f + __expf(-pre_f));
            const float gg = tanhf(pre_g);
            const float og = 1.0f / (1.0f + __expf(-pre_o));
            const float cn = fg * c_s[b][jj] + ig * gg;
            const float hn = og * tanhf(cn);
            c_s[b][jj] = cn;
            out[((size_t)t * BATCH + b) * HID + j] = hn;
            if (t == T_STEPS - 1) {
                tailp[b * HID + j] = hn;                              // h_T
                tailp[(size_t)BATCH * HID + b * HID + j] = cn;        // c_T
            }
            // repack hn into fragment planes, parity par^1 (v4-verified idx)
            const int parn = par ^ 1;
            const unsigned short hhi = f2bf(hn);
            const unsigned short hlo = f2bf(hn - bf2f(hhi));
            const size_t idx = ((((size_t)parn * 32 + (j >> 5)) * 4 + (b >> 4)) * 64
                                + ((b & 15) + 16 * ((j & 31) >> 3))) * 8 + (j & 7);
            hPHi[idx] = hhi;
            hPLo[idx] = hlo;
        }
        grid.sync();   // device-scope release/acquire: h planes visible grid-wide
    }
#undef LDA
#undef LDB
}

// ---------------------------------------------------------------------------
// Fallback (proven v2): fused fp32 per-step kernel, wave-private LDS staging.
// ---------------------------------------------------------------------------
__global__ __launch_bounds__(512) void lstm_step_f32(
    const float* __restrict__ x, const float* __restrict__ hprev,
    const float* __restrict__ cprev,
    const float* __restrict__ Wih, const float* __restrict__ Whh,
    const float* __restrict__ bih, const float* __restrict__ bhh,
    float* __restrict__ cnext, float* __restrict__ hout,
    float* __restrict__ tail)
{
    __shared__ float h_s[8][16][68];
    __shared__ float w_s[8][16][20];
    __shared__ float gates_s[64][17];
    float* part_s = &h_s[0][0][0];

    const int bid = blockIdx.x;
    const int tid = threadIdx.x;
    const int j0  = bid * 4;
    const int wv  = tid >> 6;
    const int gl  = tid & 63;
    const int b0  = (gl >> 2) * 4;
    const int c0_ = (gl & 3) * 4;

    const float* __restrict__ src = (wv < 4) ? x   : hprev;
    const float* __restrict__ W   = (wv < 4) ? Wih : Whh;
    const int kbase = (wv & 3) * 256;

    float acc[4][4] = {};
    float4 hv[4], wvf;

#pragma unroll
    for (int r = 0; r < 4; ++r) {
        const int fidx = r * 64 + gl;
        hv[r] = *(const float4*)(src + (fidx >> 2) * DIM + kbase + (fidx & 3) * 4);
    }
    {
        const int c = gl >> 2, k4 = (gl & 3) * 4;
        const int n = (c >> 2) * HID + j0 + (c & 3);
        wvf = *(const float4*)(W + (size_t)n * DIM + kbase + k4);
    }

    for (int ci = 0; ci < 16; ++ci) {
#pragma unroll
        for (int r = 0; r < 4; ++r) {
            const int fidx = r * 64 + gl;
            const int b = fidx >> 2, k4 = (fidx & 3) * 4;
            h_s[wv][k4 + 0][b] = hv[r].x; h_s[wv][k4 + 1][b] = hv[r].y;
            h_s[wv][k4 + 2][b] = hv[r].z; h_s[wv][k4 + 3][b] = hv[r].w;
        }
        {
            const int c = gl >> 2, k4 = (gl & 3) * 4;
            w_s[wv][k4 + 0][c] = wvf.x; w_s[wv][k4 + 1][c] = wvf.y;
            w_s[wv][k4 + 2][c] = wvf.z; w_s[wv][k4 + 3][c] = wvf.w;
        }
        if (ci < 15) {
            const int kb = kbase + (ci + 1) * 16;
#pragma unroll
            for (int r = 0; r < 4; ++r) {
                const int fidx = r * 64 + gl;
                hv[r] = *(const float4*)(src + (fidx >> 2) * DIM + kb + (fidx & 3) * 4);
            }
            {
                const int c = gl >> 2, k4 = (gl & 3) * 4;
                const int n = (c >> 2) * HID + j0 + (c & 3);
                wvf = *(const float4*)(W + (size_t)n * DIM + kb + k4);
            }
        }
#pragma unroll
        for (int kk = 0; kk < 16; ++kk) {
            const float4 h4 = *(const float4*)&h_s[wv][kk][b0];
            const float4 w4 = *(const float4*)&w_s[wv][kk][c0_];
            const float hr[4] = {h4.x, h4.y, h4.z, h4.w};
            const float wr[4] = {w4.x, w4.y, w4.z, w4.w};
#pragma unroll
            for (int i = 0; i < 4; ++i)
#pragma unroll
                for (int j = 0; j < 4; ++j)
                    acc[i][j] += hr[i] * wr[j];
        }
    }

    __syncthreads();
#pragma unroll
    for (int i = 0; i < 4; ++i)
#pragma unroll
        for (int j = 0; j < 4; ++j)
            part_s[tid * 17 + i * 4 + j] = acc[i][j];
    __syncthreads();
    if (tid < 64) {
#pragma unroll
        for (int i = 0; i < 4; ++i)
#pragma unroll
            for (int j = 0; j < 4; ++j) {
                const int idx = i * 4 + j;
                float s = 0.0f;
#pragma unroll
                for (int p = 0; p < 8; ++p)
                    s += part_s[(gl + 64 * p) * 17 + idx];
                gates_s[b0 + i][c0_ + j] = s;
            }
    }
    __syncthreads();

    if (tid < 256) {
        const int b  = tid >> 2;
        const int jj = tid & 3;
        const int j  = j0 + jj;
        const float pre_i = gates_s[b][0  + jj] + bih[0 * HID + j] + bhh[0 * HID + j];
        const float pre_f = gates_s[b][4  + jj] + bih[1 * HID + j] + bhh[1 * HID + j];
        const float pre_g = gates_s[b][8  + jj] + bih[2 * HID + j] + bhh[2 * HID + j];
        const float pre_o = gates_s[b][12 + jj] + bih[3 * HID + j] + bhh[3 * HID + j];
        const float ig = 1.0f / (1.0f + __expf(-pre_i));
        const float fg = 1.0f / (1.0f + __expf(-pre_f));
        const float gg = tanhf(pre_g);
        const float og = 1.0f / (1.0f + __expf(-pre_o));
        const float cp = cprev[b * HID + j];
        const float cn = fg * cp + ig * gg;
        const float hn = og * tanhf(cn);
        cnext[b * HID + j] = cn;
        hout[b * HID + j]  = hn;
        if (tail) {
            tail[b * HID + j] = hn;
            tail[(size_t)BATCH * HID + b * HID + j] = cn;
        }
    }
}

// ---------------------------------------------------------------------------
extern "C" void kernel_launch(void* const* d_in, const int* in_sizes, int n_in,
                              void* d_out, int out_size, void* d_ws, size_t ws_size,
                              hipStream_t stream) {
    const float* inputs = (const float*)d_in[0];
    const float* h0     = (const float*)d_in[1];
    const float* c0     = (const float*)d_in[2];
    const float* W_ih   = (const float*)d_in[3];
    const float* W_hh   = (const float*)d_in[4];
    const float* b_ih   = (const float*)d_in[5];
    const float* b_hh   = (const float*)d_in[6];
    float* out = (float*)d_out;

    const size_t XP = (size_t)T_STEPS * 32 * 4 * 512;  // 33,554,432 shorts/plane
    const size_t WP = (size_t)256 * 64 * 512;          //  8,388,608
    const size_t HP = (size_t)2 * 32 * 4 * 512;        //    131,072
    const size_t needB = (2 * XP + 2 * WP + 2 * HP) * sizeof(unsigned short)
                       + (size_t)BATCH * HID * sizeof(float);   // == v4's (proven fit)

    if (ws_size >= needB) {
        unsigned short* xPHi = (unsigned short*)d_ws;
        unsigned short* xPLo = xPHi + XP;
        unsigned short* wPHi = xPLo + XP;
        unsigned short* wPLo = wPHi + WP;
        unsigned short* hPHi = wPLo + WP;
        unsigned short* hPLo = hPHi + HP;
        float* tailp = out + (size_t)T_STEPS * BATCH * HID;

        pack_x<<<dim3(16384), dim3(256), 0, stream>>>(inputs, xPHi, xPLo);
        pack_w<<<dim3(4096),  dim3(256), 0, stream>>>(W_ih, W_hh, wPHi, wPLo);
        pack_h0<<<dim3(32),   dim3(256), 0, stream>>>(h0, hPHi, hPLo);

        void* args[] = {(void*)&xPHi, (void*)&xPLo, (void*)&wPHi, (void*)&wPLo,
                        (void*)&hPHi, (void*)&hPLo, (void*)&c0,
                        (void*)&b_ih, (void*)&b_hh, (void*)&out, (void*)&tailp};
        hipLaunchCooperativeKernel((void*)lstm_persist, dim3(256), dim3(512),
                                   args, 0, stream);
    } else {
        float* cbuf = (float*)d_ws;
        for (int t = 0; t < T_STEPS; ++t) {
            const float* x  = inputs + (size_t)t * BATCH * DIM;
            const float* hp = (t == 0) ? h0 : out + (size_t)(t - 1) * BATCH * HID;
            const float* cp = (t == 0) ? c0 : cbuf;
            float* ho    = out + (size_t)t * BATCH * HID;
            float* tailp = (t == T_STEPS - 1)
                         ? out + (size_t)T_STEPS * BATCH * HID : nullptr;
            lstm_step_f32<<<dim3(256), dim3(512), 0, stream>>>(
                x, hp, cp, W_ih, W_hh, b_ih, b_hh, cbuf, ho, tailp);
        }
    }
}

// Round 8
// 15374.681 us; speedup vs baseline: 1.4088x; 1.4088x over previous
//
#include <hip/hip_runtime.h>
#include <hip/hip_cooperative_groups.h>

namespace cg = cooperative_groups;

#define T_STEPS 512
#define BATCH   64
#define DIM     1024
#define HID     1024
#define G4      4096   // 4*HID
#define NBLK    256

typedef __attribute__((ext_vector_type(8))) short s8v;    // 8 bf16 = 4 VGPR
typedef __attribute__((ext_vector_type(4))) float f32x4;

__device__ __forceinline__ unsigned short f2bf(float f) {
    unsigned int u = __float_as_uint(f);
    u = u + 0x7FFFu + ((u >> 16) & 1u);       // RNE; values bounded, no inf/nan
    return (unsigned short)(u >> 16);
}
__device__ __forceinline__ float bf2f(unsigned short s) {
    return __uint_as_float(((unsigned int)s) << 16);
}

// device(agent)-scope helpers: compile to loads/stores with device-scope cache
// bits (bypass L1/L2, coherent at Infinity Cache) — no L2 invalidates needed.
__device__ __forceinline__ s8v ld_frag_dev(const unsigned short* p) {
    const unsigned int* q = (const unsigned int*)p;
    union { s8v v; unsigned int u[4]; } r;
    r.u[0] = __hip_atomic_load(q + 0, __ATOMIC_RELAXED, __HIP_MEMORY_SCOPE_AGENT);
    r.u[1] = __hip_atomic_load(q + 1, __ATOMIC_RELAXED, __HIP_MEMORY_SCOPE_AGENT);
    r.u[2] = __hip_atomic_load(q + 2, __ATOMIC_RELAXED, __HIP_MEMORY_SCOPE_AGENT);
    r.u[3] = __hip_atomic_load(q + 3, __ATOMIC_RELAXED, __HIP_MEMORY_SCOPE_AGENT);
    return r.v;
}
__device__ __forceinline__ void st_dev_u16(unsigned short* p, unsigned short v) {
    __hip_atomic_store(p, v, __ATOMIC_RELAXED, __HIP_MEMORY_SCOPE_AGENT);
}

// ---------------------------------------------------------------------------
// Fragment convention (A and B share it -> result exact for any HW k-order):
//   A: row = l&15, k = ks*32 + (l>>4)*8 + e     (row = batch within m-tile)
//   B: col = l&15, k = ks*32 + (l>>4)*8 + e     (col = gate-col c)
//   D (m89-verified): col = l&15, row = (l>>4)*4 + reg
// Packed planes (hi/lo separate):
//   xP[t][ks<32][m][l][e]   : idx = (((t*32+ks)*4+m)*64+l)*8+e
//   wP[bid][ks<64][l][e]    : ks<32 -> W_ih, ks>=32 -> W_hh
//   hP[par][ks<32][m][l][e]
// Identical layouts/arithmetic to the PASSING v4 kernel (absmax 0.0039).
// ---------------------------------------------------------------------------

__global__ __launch_bounds__(256) void pack_x(
    const float* __restrict__ inp, unsigned short* __restrict__ hi,
    unsigned short* __restrict__ lo)
{
    const size_t tau = (size_t)blockIdx.x * 256 + threadIdx.x;  // < 4,194,304
    const int l  = (int)(tau & 63);
    const int m  = (int)((tau >> 6) & 3);
    const int ks = (int)((tau >> 8) & 31);
    const int t  = (int)(tau >> 13);
    const int b  = 16 * m + (l & 15);
    const int k  = ks * 32 + (l >> 4) * 8;
    const float* src = inp + ((size_t)t * BATCH + b) * DIM + k;
    float f[8];
    *(float4*)&f[0] = *(const float4*)src;
    *(float4*)&f[4] = *(const float4*)(src + 4);
    s8v vh, vl;
#pragma unroll
    for (int e = 0; e < 8; ++e) {
        const unsigned short h8 = f2bf(f[e]);
        vh[e] = (short)h8;
        vl[e] = (short)f2bf(f[e] - bf2f(h8));
    }
    *(s8v*)(hi + tau * 8) = vh;
    *(s8v*)(lo + tau * 8) = vl;
}

__global__ __launch_bounds__(256) void pack_w(
    const float* __restrict__ Wih, const float* __restrict__ Whh,
    unsigned short* __restrict__ hi, unsigned short* __restrict__ lo)
{
    const size_t tau = (size_t)blockIdx.x * 256 + threadIdx.x;  // < 1,048,576
    const int l   = (int)(tau & 63);
    const int ks  = (int)((tau >> 6) & 63);
    const int bid = (int)(tau >> 12);
    const int c   = l & 15;
    const int n   = (c >> 2) * HID + bid * 4 + (c & 3);
    const int k   = ks * 32 + (l >> 4) * 8;
    const float* src = (k < DIM) ? (Wih + (size_t)n * DIM + k)
                                 : (Whh + (size_t)n * HID + (k - DIM));
    float f[8];
    *(float4*)&f[0] = *(const float4*)src;
    *(float4*)&f[4] = *(const float4*)(src + 4);
    s8v vh, vl;
#pragma unroll
    for (int e = 0; e < 8; ++e) {
        const unsigned short h8 = f2bf(f[e]);
        vh[e] = (short)h8;
        vl[e] = (short)f2bf(f[e] - bf2f(h8));
    }
    *(s8v*)(hi + tau * 8) = vh;
    *(s8v*)(lo + tau * 8) = vl;
}

__global__ __launch_bounds__(256) void pack_h0(
    const float* __restrict__ h0, unsigned short* __restrict__ hi,
    unsigned short* __restrict__ lo)
{
    const size_t tau = (size_t)blockIdx.x * 256 + threadIdx.x;  // < 8192 (par=0)
    const int l  = (int)(tau & 63);
    const int m  = (int)((tau >> 6) & 3);
    const int ks = (int)(tau >> 8);
    const int b  = 16 * m + (l & 15);
    const int j  = ks * 32 + (l >> 4) * 8;
    const float* src = h0 + (size_t)b * HID + j;
    float f[8];
    *(float4*)&f[0] = *(const float4*)src;
    *(float4*)&f[4] = *(const float4*)(src + 4);
    s8v vh, vl;
#pragma unroll
    for (int e = 0; e < 8; ++e) {
        const unsigned short h8 = f2bf(f[e]);
        vh[e] = (short)h8;
        vl[e] = (short)f2bf(f[e] - bf2f(h8));
    }
    *(s8v*)(hi + tau * 8) = vh;
    *(s8v*)(lo + tau * 8) = vl;
}

// ---------------------------------------------------------------------------
// One K-half of the gate GEMM: 16 k-steps, 2 m-tiles, 3-pass split precision.
// DEV=true reads A fragments with device-scope loads (h planes: written by
// other blocks each step; must bypass L1/L2). DEV=false: normal cached loads
// (x planes: read-only -> stays L2-hot since we never invalidate).
// ---------------------------------------------------------------------------
template <bool DEV>
__device__ __forceinline__ void mfma_half(
    const unsigned short* aHi, const unsigned short* aLo,
    const unsigned short* bHiP, const unsigned short* bLoP,
    const int l, const int m0, const int m1, f32x4& acc0, f32x4& acc1)
{
#define LDAX(P, i, m) (DEV ? ld_frag_dev((P) + ((size_t)(i) * 2048 + (size_t)(m) * 512 + l * 8)) \
                           : *(const s8v*)((P) + ((size_t)(i) * 2048 + (size_t)(m) * 512 + l * 8)))
#define LDBX(P, i)    (*(const s8v*)((P) + ((size_t)(i) * 512 + l * 8)))
    s8v A0h = LDAX(aHi, 0, m0), A0l = LDAX(aLo, 0, m0);
    s8v A1h = LDAX(aHi, 0, m1), A1l = LDAX(aLo, 0, m1);
    s8v Bh  = LDBX(bHiP, 0),    Bl  = LDBX(bLoP, 0);
#pragma unroll 4
    for (int i = 0; i < 16; ++i) {
        s8v nA0h, nA0l, nA1h, nA1l, nBh, nBl;
        if (i < 15) {
            nA0h = LDAX(aHi, i + 1, m0); nA0l = LDAX(aLo, i + 1, m0);
            nA1h = LDAX(aHi, i + 1, m1); nA1l = LDAX(aLo, i + 1, m1);
            nBh  = LDBX(bHiP, i + 1);    nBl  = LDBX(bLoP, i + 1);
        }
        acc0 = __builtin_amdgcn_mfma_f32_16x16x32_bf16(A0h, Bh, acc0, 0, 0, 0);
        acc1 = __builtin_amdgcn_mfma_f32_16x16x32_bf16(A1h, Bh, acc1, 0, 0, 0);
        acc0 = __builtin_amdgcn_mfma_f32_16x16x32_bf16(A0h, Bl, acc0, 0, 0, 0);
        acc1 = __builtin_amdgcn_mfma_f32_16x16x32_bf16(A1h, Bl, acc1, 0, 0, 0);
        acc0 = __builtin_amdgcn_mfma_f32_16x16x32_bf16(A0l, Bh, acc0, 0, 0, 0);
        acc1 = __builtin_amdgcn_mfma_f32_16x16x32_bf16(A1l, Bh, acc1, 0, 0, 0);
        A0h = nA0h; A0l = nA0l; A1h = nA1h; A1l = nA1l; Bh = nBh; Bl = nBl;
    }
#undef LDAX
#undef LDBX
}

// ---------------------------------------------------------------------------
// Persistent LSTM with a hand-rolled device barrier (NO cg::grid.sync —
// its per-step L2 writeback+invalidate was measured as 93% idle + 5.8 GB
// HBM refetch). Read-only x/W planes use normal cached loads and stay
// L2/L3-resident for all 512 steps; h crosses blocks via device-scope
// atomics (coherent at IC); barrier = monotonic device-scope counter.
// ---------------------------------------------------------------------------
__global__ __launch_bounds__(512) void lstm_persist(
    const unsigned short* __restrict__ xPHi, const unsigned short* __restrict__ xPLo,
    const unsigned short* __restrict__ wPHi, const unsigned short* __restrict__ wPLo,
    unsigned short* hPHi, unsigned short* hPLo,      // read par, write par^1
    const float* __restrict__ c0,
    const float* __restrict__ bih, const float* __restrict__ bhh,
    float* __restrict__ out, float* __restrict__ tailp,
    unsigned int* cnt)
{
    __shared__ float part_s[8][64][12];   // stride 12 floats: 8-way max banks
    __shared__ float gates_s[64][17];
    __shared__ float c_s[64][4];          // persistent cell state

    const int bid = blockIdx.x;
    const int tid = threadIdx.x;
    const int wv  = __builtin_amdgcn_readfirstlane(tid >> 6);
    const int l   = tid & 63;
    const int mg  = wv >> 2;             // 0..1
    const int kh  = wv & 3;              // 0..3
    const int m0  = 2 * mg, m1 = 2 * mg + 1;

    // init c state + hoist biases (tid<256 handles (b, jj))
    float bsum[4];
    if (tid < 256) {
        const int b  = tid >> 2;
        const int jj = tid & 3;
        const int j  = bid * 4 + jj;
        c_s[b][jj] = c0[b * HID + j];
#pragma unroll
        for (int g = 0; g < 4; ++g)
            bsum[g] = bih[g * HID + j] + bhh[g * HID + j];
    }
    __syncthreads();

    const unsigned short* bHiP = wPHi + ((size_t)bid * 64 + kh * 16) * 512;
    const unsigned short* bLoP = wPLo + ((size_t)bid * 64 + kh * 16) * 512;

    for (int t = 0; t < T_STEPS; ++t) {
        const int par = t & 1;

        f32x4 acc0 = {0.f, 0.f, 0.f, 0.f};
        f32x4 acc1 = {0.f, 0.f, 0.f, 0.f};

        if (kh < 2) {
            const size_t base = (((size_t)t * 32 + kh * 16) * 4) * 512;
            mfma_half<false>(xPHi + base, xPLo + base, bHiP, bLoP,
                             l, m0, m1, acc0, acc1);
        } else {
            const size_t base = (((size_t)par * 32 + (kh - 2) * 16) * 4) * 512;
            mfma_half<true>(hPHi + base, hPLo + base, bHiP, bLoP,
                            l, m0, m1, acc0, acc1);
        }

        // --- 4-way k-reduce through LDS (2 barriers) ---
        *(f32x4*)&part_s[wv][l][0] = acc0;
        *(f32x4*)&part_s[wv][l][4] = acc1;
        __syncthreads();
        if (tid < 128) {
            const int mg2 = tid >> 6, l2 = tid & 63;
            f32x4 s0 = {0.f, 0.f, 0.f, 0.f};
            f32x4 s1 = {0.f, 0.f, 0.f, 0.f};
#pragma unroll
            for (int k = 0; k < 4; ++k) {
                s0 += *(const f32x4*)&part_s[mg2 * 4 + k][l2][0];
                s1 += *(const f32x4*)&part_s[mg2 * 4 + k][l2][4];
            }
            const int c = l2 & 15, rb = (l2 >> 4) * 4;
#pragma unroll
            for (int r = 0; r < 4; ++r) {
                gates_s[16 * (2 * mg2 + 0) + rb + r][c] = s0[r];
                gates_s[16 * (2 * mg2 + 1) + rb + r][c] = s1[r];
            }
        }
        __syncthreads();

        // --- elementwise LSTM cell update + h repack for next step ---
        if (tid < 256) {
            const int b  = tid >> 2;
            const int jj = tid & 3;
            const int j  = bid * 4 + jj;
            const float pre_i = gates_s[b][0  + jj] + bsum[0];
            const float pre_f = gates_s[b][4  + jj] + bsum[1];
            const float pre_g = gates_s[b][8  + jj] + bsum[2];
            const float pre_o = gates_s[b][12 + jj] + bsum[3];
            const float ig = 1.0f / (1.0f + __expf(-pre_i));
            const float fg = 1.0f / (1.0f + __expf(-pre_f));
            const float gg = tanhf(pre_g);
            const float og = 1.0f / (1.0f + __expf(-pre_o));
            const float cn = fg * c_s[b][jj] + ig * gg;
            const float hn = og * tanhf(cn);
            c_s[b][jj] = cn;
            out[((size_t)t * BATCH + b) * HID + j] = hn;     // pure output
            if (t == T_STEPS - 1) {
                tailp[b * HID + j] = hn;                              // h_T
                tailp[(size_t)BATCH * HID + b * HID + j] = cn;        // c_T
            }
            // repack hn into fragment planes (device-scope stores -> IC)
            const int parn = par ^ 1;
            const unsigned short hhi = f2bf(hn);
            const unsigned short hlo = f2bf(hn - bf2f(hhi));
            const size_t idx = ((((size_t)parn * 32 + (j >> 5)) * 4 + (b >> 4)) * 64
                                + ((b & 15) + 16 * ((j & 31) >> 3))) * 8 + (j & 7);
            st_dev_u16(hPHi + idx, hhi);
            st_dev_u16(hPLo + idx, hlo);
        }

        // --- lightweight device barrier (no L2 writeback/invalidate) ---
        if (t < T_STEPS - 1) {
            __syncthreads();   // all waves drain vmcnt -> h stores at IC
            if (tid == 0) {
                atomicAdd(cnt, 1u);   // device-scope
                const unsigned int target = (unsigned int)NBLK * (t + 1);
                while (__hip_atomic_load(cnt, __ATOMIC_RELAXED,
                                         __HIP_MEMORY_SCOPE_AGENT) < target)
                    __builtin_amdgcn_s_sleep(4);
            }
            __syncthreads();
        }
    }
}

// ---------------------------------------------------------------------------
// Fallback (proven v2): fused fp32 per-step kernel, wave-private LDS staging.
// ---------------------------------------------------------------------------
__global__ __launch_bounds__(512) void lstm_step_f32(
    const float* __restrict__ x, const float* __restrict__ hprev,
    const float* __restrict__ cprev,
    const float* __restrict__ Wih, const float* __restrict__ Whh,
    const float* __restrict__ bih, const float* __restrict__ bhh,
    float* __restrict__ cnext, float* __restrict__ hout,
    float* __restrict__ tail)
{
    __shared__ float h_s[8][16][68];
    __shared__ float w_s[8][16][20];
    __shared__ float gates_s[64][17];
    float* part_s = &h_s[0][0][0];

    const int bid = blockIdx.x;
    const int tid = threadIdx.x;
    const int j0  = bid * 4;
    const int wv  = tid >> 6;
    const int gl  = tid & 63;
    const int b0  = (gl >> 2) * 4;
    const int c0_ = (gl & 3) * 4;

    const float* __restrict__ src = (wv < 4) ? x   : hprev;
    const float* __restrict__ W   = (wv < 4) ? Wih : Whh;
    const int kbase = (wv & 3) * 256;

    float acc[4][4] = {};
    float4 hv[4], wvf;

#pragma unroll
    for (int r = 0; r < 4; ++r) {
        const int fidx = r * 64 + gl;
        hv[r] = *(const float4*)(src + (fidx >> 2) * DIM + kbase + (fidx & 3) * 4);
    }
    {
        const int c = gl >> 2, k4 = (gl & 3) * 4;
        const int n = (c >> 2) * HID + j0 + (c & 3);
        wvf = *(const float4*)(W + (size_t)n * DIM + kbase + k4);
    }

    for (int ci = 0; ci < 16; ++ci) {
#pragma unroll
        for (int r = 0; r < 4; ++r) {
            const int fidx = r * 64 + gl;
            const int b = fidx >> 2, k4 = (fidx & 3) * 4;
            h_s[wv][k4 + 0][b] = hv[r].x; h_s[wv][k4 + 1][b] = hv[r].y;
            h_s[wv][k4 + 2][b] = hv[r].z; h_s[wv][k4 + 3][b] = hv[r].w;
        }
        {
            const int c = gl >> 2, k4 = (gl & 3) * 4;
            w_s[wv][k4 + 0][c] = wvf.x; w_s[wv][k4 + 1][c] = wvf.y;
            w_s[wv][k4 + 2][c] = wvf.z; w_s[wv][k4 + 3][c] = wvf.w;
        }
        if (ci < 15) {
            const int kb = kbase + (ci + 1) * 16;
#pragma unroll
            for (int r = 0; r < 4; ++r) {
                const int fidx = r * 64 + gl;
                hv[r] = *(const float4*)(src + (fidx >> 2) * DIM + kb + (fidx & 3) * 4);
            }
            {
                const int c = gl >> 2, k4 = (gl & 3) * 4;
                const int n = (c >> 2) * HID + j0 + (c & 3);
                wvf = *(const float4*)(W + (size_t)n * DIM + kb + k4);
            }
        }
#pragma unroll
        for (int kk = 0; kk < 16; ++kk) {
            const float4 h4 = *(const float4*)&h_s[wv][kk][b0];
            const float4 w4 = *(const float4*)&w_s[wv][kk][c0_];
            const float hr[4] = {h4.x, h4.y, h4.z, h4.w};
            const float wr[4] = {w4.x, w4.y, w4.z, w4.w};
#pragma unroll
            for (int i = 0; i < 4; ++i)
#pragma unroll
                for (int j = 0; j < 4; ++j)
                    acc[i][j] += hr[i] * wr[j];
        }
    }

    __syncthreads();
#pragma unroll
    for (int i = 0; i < 4; ++i)
#pragma unroll
        for (int j = 0; j < 4; ++j)
            part_s[tid * 17 + i * 4 + j] = acc[i][j];
    __syncthreads();
    if (tid < 64) {
#pragma unroll
        for (int i = 0; i < 4; ++i)
#pragma unroll
            for (int j = 0; j < 4; ++j) {
                const int idx = i * 4 + j;
                float s = 0.0f;
#pragma unroll
                for (int p = 0; p < 8; ++p)
                    s += part_s[(gl + 64 * p) * 17 + idx];
                gates_s[b0 + i][c0_ + j] = s;
            }
    }
    __syncthreads();

    if (tid < 256) {
        const int b  = tid >> 2;
        const int jj = tid & 3;
        const int j  = j0 + jj;
        const float pre_i = gates_s[b][0  + jj] + bih[0 * HID + j] + bhh[0 * HID + j];
        const float pre_f = gates_s[b][4  + jj] + bih[1 * HID + j] + bhh[1 * HID + j];
        const float pre_g = gates_s[b][8  + jj] + bih[2 * HID + j] + bhh[2 * HID + j];
        const float pre_o = gates_s[b][12 + jj] + bih[3 * HID + j] + bhh[3 * HID + j];
        const float ig = 1.0f / (1.0f + __expf(-pre_i));
        const float fg = 1.0f / (1.0f + __expf(-pre_f));
        const float gg = tanhf(pre_g);
        const float og = 1.0f / (1.0f + __expf(-pre_o));
        const float cp = cprev[b * HID + j];
        const float cn = fg * cp + ig * gg;
        const float hn = og * tanhf(cn);
        cnext[b * HID + j] = cn;
        hout[b * HID + j]  = hn;
        if (tail) {
            tail[b * HID + j] = hn;
            tail[(size_t)BATCH * HID + b * HID + j] = cn;
        }
    }
}

// ---------------------------------------------------------------------------
extern "C" void kernel_launch(void* const* d_in, const int* in_sizes, int n_in,
                              void* d_out, int out_size, void* d_ws, size_t ws_size,
                              hipStream_t stream) {
    const float* inputs = (const float*)d_in[0];
    const float* h0     = (const float*)d_in[1];
    const float* c0     = (const float*)d_in[2];
    const float* W_ih   = (const float*)d_in[3];
    const float* W_hh   = (const float*)d_in[4];
    const float* b_ih   = (const float*)d_in[5];
    const float* b_hh   = (const float*)d_in[6];
    float* out = (float*)d_out;

    const size_t XP = (size_t)T_STEPS * 32 * 4 * 512;  // 33,554,432 shorts/plane
    const size_t WP = (size_t)256 * 64 * 512;          //  8,388,608
    const size_t HP = (size_t)2 * 32 * 4 * 512;        //    131,072
    const size_t needB = (2 * XP + 2 * WP + 2 * HP) * sizeof(unsigned short)
                       + (size_t)BATCH * HID * sizeof(float);   // == v4's (proven fit)

    if (ws_size >= needB) {
        unsigned short* xPHi = (unsigned short*)d_ws;
        unsigned short* xPLo = xPHi + XP;
        unsigned short* wPHi = xPLo + XP;
        unsigned short* wPLo = wPHi + WP;
        unsigned short* hPHi = wPLo + WP;
        unsigned short* hPLo = hPHi + HP;
        unsigned int* cnt = (unsigned int*)(hPLo + HP);  // lives in cbuf slot
        float* tailp = out + (size_t)T_STEPS * BATCH * HID;

        pack_x<<<dim3(16384), dim3(256), 0, stream>>>(inputs, xPHi, xPLo);
        pack_w<<<dim3(4096),  dim3(256), 0, stream>>>(W_ih, W_hh, wPHi, wPLo);
        pack_h0<<<dim3(32),   dim3(256), 0, stream>>>(h0, hPHi, hPLo);
        hipMemsetAsync(cnt, 0, sizeof(unsigned int), stream);

        void* args[] = {(void*)&xPHi, (void*)&xPLo, (void*)&wPHi, (void*)&wPLo,
                        (void*)&hPHi, (void*)&hPLo, (void*)&c0,
                        (void*)&b_ih, (void*)&b_hh, (void*)&out, (void*)&tailp,
                        (void*)&cnt};
        hipLaunchCooperativeKernel((void*)lstm_persist, dim3(NBLK), dim3(512),
                                   args, 0, stream);
    } else {
        float* cbuf = (float*)d_ws;
        for (int t = 0; t < T_STEPS; ++t) {
            const float* x  = inputs + (size_t)t * BATCH * DIM;
            const float* hp = (t == 0) ? h0 : out + (size_t)(t - 1) * BATCH * HID;
            const float* cp = (t == 0) ? c0 : cbuf;
            float* ho    = out + (size_t)t * BATCH * HID;
            float* tailp = (t == T_STEPS - 1)
                         ? out + (size_t)T_STEPS * BATCH * HID : nullptr;
            lstm_step_f32<<<dim3(256), dim3(512), 0, stream>>>(
                x, hp, cp, W_ih, W_hh, b_ih, b_hh, cbuf, ho, tailp);
        }
    }
}